// Round 1
// baseline (605.438 us; speedup 1.0000x reference)
//
#include <hip/hip_runtime.h>

// Problem constants
// N=8, T_y=300, T_x=160, E=256, E/2=128, 3E=768
// d_out: [attn 8*300*160 = 384000][outputs 8*300*256 = 614400][hidden 2048]

typedef _Float16 f16x8 __attribute__((ext_vector_type(8)));
typedef float f32x4 __attribute__((ext_vector_type(4)));

__device__ __forceinline__ float fexp2(float x) { return __builtin_amdgcn_exp2f(x); }
__device__ __forceinline__ float frcp(float x) { return __builtin_amdgcn_rcpf(x); }
// sigmoid(x) = 1/(1+2^(-x*log2 e))
__device__ __forceinline__ float fsig(float x) {
    return frcp(1.0f + fexp2(x * -1.4426950408889634f));
}
// tanh(y) = 1 - 2/(1+2^(y*2*log2 e)); saturates correctly at +-inf args
__device__ __forceinline__ float ftanh(float x) {
    return 1.0f - 2.0f * frcp(1.0f + fexp2(x * 2.8853900817779268f));
}

// ---------------------------------------------------------------------------
// Kernel A: repack Whh (f32 [768][256]) into fp16 MFMA A-fragments.
// Layout consumed by gru_kernel: planes p = rt*8+kt (48 planes), within plane
// thread (w,lane) -> 8 f16 (one A-frag, 16B). rt = g*2+t1; wave w owns hidden
// slice [w*32, w*32+32): rows g*256 + w*32 + t1*16 + (lane&15),
// k = kt*32 + (lane>>4)*8 + j.
// ---------------------------------------------------------------------------
__global__ __launch_bounds__(256) void prep_whh(const float* __restrict__ Whh,
                                                f16x8* __restrict__ wa) {
    int tid = blockIdx.x * 256 + threadIdx.x;   // 0..24575 = 48*512
    int p = tid >> 9;          // plane 0..47
    int r3 = tid & 511;        // w*64+lane
    int w = r3 >> 6, lane = r3 & 63;
    int rt = p >> 3, kt = p & 7;
    int g = rt >> 1, t1 = rt & 1;
    int row = g * 256 + w * 32 + t1 * 16 + (lane & 15);
    int k0 = kt * 32 + (lane >> 4) * 8;
    const float* s = Whh + (size_t)row * 256 + k0;
    f16x8 v;
#pragma unroll
    for (int i = 0; i < 8; ++i) v[i] = (_Float16)s[i];
    wa[tid] = v;
}

// ---------------------------------------------------------------------------
// Kernel B: generic f32 tiled GEMM  C[M,N] = X[M,K] @ Wt[N,K]^T
// mode 0: C f32 natural [row*N+col]
// mode 1: gi scatter: row=(b*300+t) -> store at (t*8+b)*768+col, bias folded
//         (bih+bhh for r,z gates; bih only for n gate)
// mode 2: C16 f16 natural
// BM=BN=64, BK=32, 256 threads, 4x4 per thread.
// ---------------------------------------------------------------------------
__global__ __launch_bounds__(256) void gemm_kernel(
    const float* __restrict__ X, const float* __restrict__ Wt,
    float* __restrict__ C, _Float16* __restrict__ C16,
    const float* __restrict__ bih, const float* __restrict__ bhh,
    int M, int N, int K, int mode) {
    __shared__ float Xs[32][65];
    __shared__ float Ws2[32][65];
    const int n0 = blockIdx.x * 64, m0 = blockIdx.y * 64;
    const int tid = threadIdx.x;
    const int tx = tid & 15, ty = tid >> 4;
    float acc[4][4] = {};
    for (int k0 = 0; k0 < K; k0 += 32) {
#pragma unroll
        for (int i = 0; i < 8; ++i) {
            int e = tid + i * 256;
            int kk = e & 31, m = e >> 5;
            int row = m0 + m;
            Xs[kk][m] = (row < M) ? X[(size_t)row * K + k0 + kk] : 0.0f;
            Ws2[kk][m] = Wt[(size_t)(n0 + m) * K + k0 + kk];
        }
        __syncthreads();
#pragma unroll
        for (int kk = 0; kk < 32; ++kk) {
            float a[4], b[4];
#pragma unroll
            for (int i = 0; i < 4; ++i) a[i] = Xs[kk][ty * 4 + i];
#pragma unroll
            for (int j = 0; j < 4; ++j) b[j] = Ws2[kk][tx * 4 + j];
#pragma unroll
            for (int i = 0; i < 4; ++i)
#pragma unroll
                for (int j = 0; j < 4; ++j) acc[i][j] += a[i] * b[j];
        }
        __syncthreads();
    }
#pragma unroll
    for (int i = 0; i < 4; ++i) {
        int row = m0 + ty * 4 + i;
        if (row >= M) continue;
#pragma unroll
        for (int j = 0; j < 4; ++j) {
            int col = n0 + tx * 4 + j;
            float val = acc[i][j];
            if (mode == 1) {
                int b = row / 300;
                int t = row - b * 300;
                val += (col < 512) ? (bih[col] + bhh[col]) : bih[col];
                C[(size_t)(t * 8 + b) * 768 + col] = val;
            } else if (mode == 2) {
                C16[(size_t)row * N + col] = (_Float16)val;
            } else {
                C[(size_t)row * N + col] = val;
            }
        }
    }
}

// ---------------------------------------------------------------------------
// Kernel C: GRU recurrence. 8 blocks (one per batch) x 512 threads (8 waves).
// Whh fp16 A-fragments resident in VGPRs (192/thread). h fp16 double-buffered
// in LDS, broadcast as the MFMA B operand (all 16 cols identical -> every
// lane holds gh for its 4 rows). Gate-aligned tiles: wave w owns r/z/n rows
// for hidden slice [w*32,w*32+32) -> epilogue is intra-wave via 3KB LDS.
// One __syncthreads per step.
// ---------------------------------------------------------------------------
__global__ __launch_bounds__(512, 2) void gru_kernel(
    const float* __restrict__ gi, const f16x8* __restrict__ wa,
    const float* __restrict__ h0, const float* __restrict__ bhh,
    float* __restrict__ outs, float* __restrict__ hid) {
    const int b = blockIdx.x;
    const int tid = threadIdx.x;
    const int lane = tid & 63;
    const int w = tid >> 6;
    const int q = lane >> 4;
    const int u = lane & 31;
    const int j = w * 32 + u;   // hidden unit this lane finalizes (2x redundant)

    __shared__ __align__(16) _Float16 hbuf[2][256];
    __shared__ __align__(16) float ghx[8][96];   // [wave][g*32 + u]

    // Load resident A fragments: A[rt][kt], rt = g*2+t1
    f16x8 A[6][8];
#pragma unroll
    for (int rt = 0; rt < 6; ++rt)
#pragma unroll
        for (int kt = 0; kt < 8; ++kt)
            A[rt][kt] = wa[(rt * 8 + kt) * 512 + w * 64 + lane];

    float h = h0[b * 256 + j];
    const float bn = bhh[512 + j];   // bhh_n stays inside r*(.)
    if (lane < 32) hbuf[0][j] = (_Float16)h;
    __syncthreads();

    const float* gp = gi + b * 768 + j;
    float* op = outs + (size_t)b * (300 * 256) + j;

    for (int t = 0; t < 300; ++t) {
        // gi prefetch (independent of MFMAs; compiler schedules early)
        const float* g = gp + t * 6144;
        float gr = g[0], gz = g[256], gn = g[512];

        const _Float16* hb = hbuf[t & 1];
        f32x4 D0 = {0.f, 0.f, 0.f, 0.f};
        f32x4 D1 = D0, D2 = D0, D3 = D0, D4 = D0, D5 = D0;
#pragma unroll
        for (int kt = 0; kt < 8; ++kt) {
            f16x8 B = *(const f16x8*)(hb + kt * 32 + q * 8);  // broadcast read
            D0 = __builtin_amdgcn_mfma_f32_16x16x32_f16(A[0][kt], B, D0, 0, 0, 0);
            D1 = __builtin_amdgcn_mfma_f32_16x16x32_f16(A[1][kt], B, D1, 0, 0, 0);
            D2 = __builtin_amdgcn_mfma_f32_16x16x32_f16(A[2][kt], B, D2, 0, 0, 0);
            D3 = __builtin_amdgcn_mfma_f32_16x16x32_f16(A[3][kt], B, D3, 0, 0, 0);
            D4 = __builtin_amdgcn_mfma_f32_16x16x32_f16(A[4][kt], B, D4, 0, 0, 0);
            D5 = __builtin_amdgcn_mfma_f32_16x16x32_f16(A[5][kt], B, D5, 0, 0, 0);
        }
        // Intra-wave gate exchange: all D columns identical; col-0 lanes write.
        // ghx[w][g*32 + t1*16 + q*4 + i] = gh_g[w*32 + t1*16 + q*4 + i]
        if ((lane & 15) == 0) {
            *(f32x4*)&ghx[w][q * 4] = D0;
            *(f32x4*)&ghx[w][16 + q * 4] = D1;
            *(f32x4*)&ghx[w][32 + q * 4] = D2;
            *(f32x4*)&ghx[w][48 + q * 4] = D3;
            *(f32x4*)&ghx[w][64 + q * 4] = D4;
            *(f32x4*)&ghx[w][80 + q * 4] = D5;
        }
        __threadfence_block();   // lgkmcnt drain; intra-wave visibility
        float vr = ghx[w][u];
        float vz = ghx[w][32 + u];
        float vn = ghx[w][64 + u];
        float r = fsig(gr + vr);
        float z = fsig(gz + vz);
        float n = ftanh(gn + r * (vn + bn));
        h = n + z * (h - n);
        if (lane < 32) {
            op[t * 256] = h;
            hbuf[(t + 1) & 1][j] = (_Float16)h;
        }
        __syncthreads();
    }
    if (lane < 32) hid[b * 256 + j] = h;
}

// ---------------------------------------------------------------------------
// Kernel D: scores + softmax. Block = (t-chunk of 10, batch). Threads 0..159
// each own one x; u read as f16 from ws (L1-resident stride pattern),
// w-row and v staged in LDS (broadcast reads).
// ---------------------------------------------------------------------------
__global__ __launch_bounds__(256) void attn_kernel(
    const _Float16* __restrict__ u16, const float* __restrict__ wv,
    const float* __restrict__ v, float* __restrict__ attn) {
    const int tc = blockIdx.x, b = blockIdx.y;
    const int tid = threadIdx.x;
    __shared__ float wL[256], vL[256], sc[160], red[2];
    vL[tid] = v[tid];
    for (int ti = 0; ti < 10; ++ti) {
        int t = tc * 10 + ti;
        wL[tid] = wv[(size_t)(b * 300 + t) * 256 + tid];
        __syncthreads();
        float acc = 0.0f;
        if (tid < 160) {
            const uint32_t* ur = (const uint32_t*)(u16 + (size_t)(b * 160 + tid) * 256);
#pragma unroll 8
            for (int e2 = 0; e2 < 128; ++e2) {
                union { uint32_t uu; _Float16 hh[2]; } cv;
                cv.uu = ur[e2];
                int e = e2 * 2;
                acc += vL[e] * ftanh(wL[e] + (float)cv.hh[0]);
                acc += vL[e + 1] * ftanh(wL[e + 1] + (float)cv.hh[1]);
            }
            sc[tid] = acc;
        }
        __syncthreads();
        if (tid < 64) {
            float m = -3.0e38f;
            for (int i = tid; i < 160; i += 64) m = fmaxf(m, sc[i]);
#pragma unroll
            for (int o = 32; o; o >>= 1) m = fmaxf(m, __shfl_xor(m, o));
            if (tid == 0) red[0] = m;
        }
        __syncthreads();
        float ee = 0.0f;
        if (tid < 160) {
            ee = fexp2((acc - red[0]) * 1.4426950408889634f);
            sc[tid] = ee;
        }
        __syncthreads();
        if (tid < 64) {
            float s = 0.0f;
            for (int i = tid; i < 160; i += 64) s += sc[i];
#pragma unroll
            for (int o = 32; o; o >>= 1) s += __shfl_xor(s, o);
            if (tid == 0) red[1] = s;
        }
        __syncthreads();
        if (tid < 160)
            attn[(size_t)(b * 300 + t) * 160 + tid] = ee * frcp(red[1]);
        __syncthreads();
    }
}

// ---------------------------------------------------------------------------
// ws layout (bytes):
//   [0, 7372800)        gi f32 [(t*8+b)*768 + col]           (live: K1b..K2)
//   [7372800, 7766016)  Whh fp16 A-fragments                 (live: prep..K2)
//   [0, 655360)         u f16 [b*160+x][256]   (aliases dead gi, post-K2)
//   [655360, 3112960)   w f32 [b*300+t][256]   (aliases dead gi, post-K2)
// ---------------------------------------------------------------------------
extern "C" void kernel_launch(void* const* d_in, const int* in_sizes, int n_in,
                              void* d_out, int out_size, void* d_ws, size_t ws_size,
                              hipStream_t stream) {
    const float* inputs = (const float*)d_in[0];
    const float* memory = (const float*)d_in[1];
    const float* h0 = (const float*)d_in[2];
    const float* Wih = (const float*)d_in[3];
    const float* Whh = (const float*)d_in[4];
    const float* bih = (const float*)d_in[5];
    const float* bhh = (const float*)d_in[6];
    const float* Wm = (const float*)d_in[7];
    const float* Um = (const float*)d_in[8];
    const float* vv = (const float*)d_in[9];

    float* out = (float*)d_out;
    float* out_attn = out;              // 384000
    float* out_outputs = out + 384000;  // 614400
    float* out_hidden = out + 998400;   // 2048

    char* ws = (char*)d_ws;
    float* gi = (float*)ws;
    f16x8* wa = (f16x8*)(ws + 7372800);
    _Float16* u16 = (_Float16*)ws;
    float* wbuf = (float*)(ws + 655360);

    // Phase 1: weight repack + gi GEMM (bias-folded, scattered)
    prep_whh<<<96, 256, 0, stream>>>(Whh, wa);
    gemm_kernel<<<dim3(12, 38), 256, 0, stream>>>(inputs, Wih, gi, nullptr,
                                                  bih, bhh, 2400, 768, 128, 1);
    // Phase 2: sequential GRU (critical path, 8 CUs, weight-stationary MFMA)
    gru_kernel<<<8, 512, 0, stream>>>(gi, wa, h0, bhh, out_outputs, out_hidden);
    // Phase 3: attention precompute + scores/softmax
    gemm_kernel<<<dim3(4, 20), 256, 0, stream>>>(memory, Um, nullptr, u16,
                                                 nullptr, nullptr, 1280, 256, 256, 2);
    gemm_kernel<<<dim3(4, 38), 256, 0, stream>>>(out_outputs, Wm, wbuf, nullptr,
                                                 nullptr, nullptr, 2400, 256, 256, 0);
    attn_kernel<<<dim3(30, 8), 256, 0, stream>>>(u16, wbuf, vv, out_attn);
}